// Round 1
// baseline (489.236 us; speedup 1.0000x reference)
//
#include <hip/hip_runtime.h>

// Problem constants (from reference setup_inputs)
constexpr int B_DIM   = 64;
constexpr int S_DIM   = 2048;
constexpr int D_DIM   = 512;      // 128 float4 per row
constexpr int NMASK   = 1536;
constexpr int NUNMASK = 512;
constexpr float ALPHA = 0.1f;

constexpr int N_MASK_TOT = B_DIM * NMASK;      // 98304
constexpr int N_UN_TOT   = B_DIM * NUNMASK;    // 32768
constexpr int N_IDX_TOT  = N_MASK_TOT + N_UN_TOT;  // 131072
constexpr int ROWS_TOTAL = B_DIM * S_DIM;          // 131072

// ---------------------------------------------------------------------------
// Kernel 1: scatter index counts into a [B, S] float weight array.
// weight[b,s] = (#times s in mask_id[b]) * wm + (#times s in unmask_id[b]) * wu
// 131072 atomics over 131072 slots -> ~1 per slot, negligible contention.
// ---------------------------------------------------------------------------
__global__ __launch_bounds__(256) void build_weights(
    const int* __restrict__ mask_id,
    const int* __restrict__ unmask_id,
    float*     __restrict__ w)
{
    const float wm = 1.0f / (float)((long long)B_DIM * NMASK   * D_DIM);
    const float wu = ALPHA / (float)((long long)B_DIM * NUNMASK * D_DIM);

    const int i = blockIdx.x * blockDim.x + threadIdx.x;
    if (i >= N_IDX_TOT) return;
    if (i < N_MASK_TOT) {
        const int b   = i / NMASK;            // magic-mul div by 1536
        const int idx = mask_id[i];
        atomicAdd(&w[(b << 11) + idx], wm);
    } else {
        const int j   = i - N_MASK_TOT;
        const int b   = j >> 9;               // / NUNMASK (512)
        const int idx = unmask_id[j];
        atomicAdd(&w[(b << 11) + idx], wu);
    }
}

// ---------------------------------------------------------------------------
// Kernel 2: weighted SSE over all rows IN MEMORY ORDER.
// One row (2 KB per tensor) per wave: 64 lanes x 2 float4 per tensor.
// Block owns 64 contiguous rows; weights prefetched to LDS so the hot loop
// has no dependent index chain. Zero-weight rows (~36.8%) are skipped
// (wave-uniform branch) -> traffic ~324 MB instead of 512 MB.
// ---------------------------------------------------------------------------
constexpr int BLOCK2          = 256;   // 4 waves
constexpr int ROWS_PER_BLOCK  = 64;    // contiguous chunk; 16 iters of 4 rows
constexpr int GRID2           = ROWS_TOTAL / ROWS_PER_BLOCK;  // 2048

__global__ __launch_bounds__(BLOCK2) void weighted_sse(
    const float* __restrict__ outputs,
    const float* __restrict__ orig,
    const float* __restrict__ w,
    float*       __restrict__ out)
{
    __shared__ float wsh[ROWS_PER_BLOCK];
    __shared__ float sdata[BLOCK2 / 64];

    const int base = blockIdx.x * ROWS_PER_BLOCK;
    if (threadIdx.x < ROWS_PER_BLOCK)
        wsh[threadIdx.x] = w[base + threadIdx.x];
    __syncthreads();

    const int wid  = threadIdx.x >> 6;   // wave id within block, 0..3
    const int lane = threadIdx.x & 63;

    float acc = 0.0f;

    #pragma unroll
    for (int i = 0; i < ROWS_PER_BLOCK / 4; ++i) {
        const int   rlocal = i * 4 + wid;            // wave-uniform
        const float wgt    = wsh[rlocal];            // wave-uniform
        if (wgt != 0.0f) {                           // uniform branch, no divergence
            const size_t off = (size_t)(base + rlocal) * D_DIM;
            const float4* po = (const float4*)(outputs + off);
            const float4* pt = (const float4*)(orig    + off);
            // 2 KB row = 128 float4; lane reads elements lane and lane+64.
            const float4 o0 = po[lane];
            const float4 o1 = po[lane + 64];
            const float4 t0 = pt[lane];
            const float4 t1 = pt[lane + 64];
            float s = 0.0f;
            {
                const float dx = o0.x - t0.x, dy = o0.y - t0.y;
                const float dz = o0.z - t0.z, dw = o0.w - t0.w;
                s += dx * dx + dy * dy + dz * dz + dw * dw;
            }
            {
                const float dx = o1.x - t1.x, dy = o1.y - t1.y;
                const float dz = o1.z - t1.z, dw = o1.w - t1.w;
                s += dx * dx + dy * dy + dz * dz + dw * dw;
            }
            acc = fmaf(wgt, s, acc);
        }
    }

    // 64-lane wave shuffle reduction
    #pragma unroll
    for (int off = 32; off > 0; off >>= 1)
        acc += __shfl_down(acc, off, 64);

    if (lane == 0) sdata[wid] = acc;
    __syncthreads();

    if (threadIdx.x == 0) {
        atomicAdd(out, sdata[0] + sdata[1] + sdata[2] + sdata[3]);
    }
}

// ---------------------------------------------------------------------------
// Fallback (previous session's verified kernel) if workspace is too small.
// ---------------------------------------------------------------------------
__global__ __launch_bounds__(256) void mae_loss_kernel(
    const float* __restrict__ outputs,
    const float* __restrict__ orig,
    const int*   __restrict__ mask_id,
    const int*   __restrict__ unmask_id,
    float*       __restrict__ out)
{
    const int lane_in_row  = threadIdx.x & 127;
    const int row_in_block = threadIdx.x >> 7;

    const float wm = 1.0f / (float)((long long)B_DIM * NMASK   * D_DIM);
    const float wu = ALPHA / (float)((long long)B_DIM * NUNMASK * D_DIM);

    float acc = 0.0f;
    for (int r = blockIdx.x * 2 + row_in_block; r < ROWS_TOTAL; r += 2048 * 2) {
        const int b = r >> 11;
        const int j = r & 2047;
        int   idx;
        float w;
        if (j < NMASK) { idx = mask_id[b * NMASK + j]; w = wm; }
        else           { idx = unmask_id[b * NUNMASK + (j - NMASK)]; w = wu; }
        const size_t row_off = ((size_t)b * S_DIM + (size_t)idx) * D_DIM;
        const float4* po = (const float4*)(outputs + row_off);
        const float4* pt = (const float4*)(orig    + row_off);
        const float4 o = po[lane_in_row];
        const float4 t = pt[lane_in_row];
        const float dx = o.x - t.x, dy = o.y - t.y;
        const float dz = o.z - t.z, dw = o.w - t.w;
        acc += w * (dx * dx + dy * dy + dz * dz + dw * dw);
    }
    #pragma unroll
    for (int off = 32; off > 0; off >>= 1)
        acc += __shfl_down(acc, off, 64);
    __shared__ float sdata[4];
    const int wid = threadIdx.x >> 6;
    if ((threadIdx.x & 63) == 0) sdata[wid] = acc;
    __syncthreads();
    if (threadIdx.x == 0) {
        float s = 0.0f;
        #pragma unroll
        for (int i = 0; i < 4; ++i) s += sdata[i];
        atomicAdd(out, s);
    }
}

extern "C" void kernel_launch(void* const* d_in, const int* in_sizes, int n_in,
                              void* d_out, int out_size, void* d_ws, size_t ws_size,
                              hipStream_t stream) {
    const float* outputs   = (const float*)d_in[0];
    const float* orig      = (const float*)d_in[1];
    const int*   mask_id   = (const int*)d_in[2];
    const int*   unmask_id = (const int*)d_in[3];
    float* out = (float*)d_out;

    // d_out is re-poisoned before every timed launch — zero it here.
    hipMemsetAsync(out, 0, sizeof(float), stream);

    const size_t wbytes = (size_t)ROWS_TOTAL * sizeof(float);  // 512 KB
    if (ws_size >= wbytes) {
        float* w = (float*)d_ws;
        hipMemsetAsync(w, 0, wbytes, stream);
        const int threads = 256;
        const int blocks  = (N_IDX_TOT + threads - 1) / threads;  // 512
        build_weights<<<blocks, threads, 0, stream>>>(mask_id, unmask_id, w);
        weighted_sse<<<GRID2, BLOCK2, 0, stream>>>(outputs, orig, w, out);
    } else {
        // Workspace too small: previous verified gather kernel.
        mae_loss_kernel<<<2048, 256, 0, stream>>>(outputs, orig, mask_id, unmask_id, out);
    }
}

// Round 2
// 482.439 us; speedup vs baseline: 1.0141x; 1.0141x over previous
//
#include <hip/hip_runtime.h>

// Problem constants (from reference setup_inputs)
constexpr int B_DIM   = 64;
constexpr int S_DIM   = 2048;
constexpr int D_DIM   = 512;      // 128 float4 per row
constexpr int NMASK   = 1536;
constexpr int NUNMASK = 512;
constexpr float ALPHA = 0.1f;

constexpr int ROWS_TOTAL = B_DIM * S_DIM;   // 131072
constexpr int RPB        = 64;              // rows per block (contiguous window)
constexpr int BLOCK      = 256;             // 4 waves
constexpr int GRID       = ROWS_TOTAL / RPB;          // 2048 blocks
constexpr int BLOCKS_PER_SAMPLE = S_DIM / RPB;        // 32

// ---------------------------------------------------------------------------
// Single fused kernel, NO workspace:
//   Phase 1: block (b, win) scans sample b's 2048 indices (8 KB, L2-resident:
//            32 blocks share each sample's indices) and histograms the ones
//            falling in its 64-row window into LDS weights.
//   Phase 2: weighted SSE over the 64 contiguous rows IN MEMORY ORDER,
//            one row per wave per iter (64 lanes x 2 float4 per tensor),
//            skipping zero-weight rows (~36.8% -> ~340 MB instead of 512 MB).
//   Phase 3: wave shuffle-reduce + one atomicAdd per block.
// ---------------------------------------------------------------------------
__global__ __launch_bounds__(BLOCK) void fused_mae_loss(
    const float* __restrict__ outputs,
    const float* __restrict__ orig,
    const int*   __restrict__ mask_id,
    const int*   __restrict__ unmask_id,
    float*       __restrict__ out)
{
    __shared__ float wsh[RPB];
    __shared__ float sred[BLOCK / 64];

    const int tid = threadIdx.x;
    const int b   = blockIdx.x >> 5;                   // / BLOCKS_PER_SAMPLE
    const int win = (blockIdx.x & (BLOCKS_PER_SAMPLE - 1)) * RPB;

    if (tid < RPB) wsh[tid] = 0.0f;
    __syncthreads();

    const float wm = 1.0f / (float)((long long)B_DIM * NMASK   * D_DIM);
    const float wu = ALPHA / (float)((long long)B_DIM * NUNMASK * D_DIM);

    // ---- Phase 1: LDS histogram of this window's weights ----
    {
        const int* mp = mask_id + b * NMASK;
        #pragma unroll
        for (int k = 0; k < NMASK / BLOCK; ++k) {      // 6 iters
            const int idx = mp[k * BLOCK + tid];
            const unsigned loc = (unsigned)(idx - win);
            if (loc < (unsigned)RPB) atomicAdd(&wsh[loc], wm);
        }
        const int* up = unmask_id + b * NUNMASK;
        #pragma unroll
        for (int k = 0; k < NUNMASK / BLOCK; ++k) {    // 2 iters
            const int idx = up[k * BLOCK + tid];
            const unsigned loc = (unsigned)(idx - win);
            if (loc < (unsigned)RPB) atomicAdd(&wsh[loc], wu);
        }
    }
    __syncthreads();

    // ---- Phase 2: streaming weighted SSE ----
    const int wid  = tid >> 6;   // 0..3
    const int lane = tid & 63;
    const size_t base_off = ((size_t)b * S_DIM + (size_t)win) * D_DIM;

    float acc = 0.0f;

    #pragma unroll
    for (int i = 0; i < RPB / 4; ++i) {                // 16 iters, 4 rows each
        const int   rloc = i * 4 + wid;                // wave-uniform
        const float wgt  = wsh[rloc];                  // wave-uniform (LDS)
        if (wgt != 0.0f) {                             // uniform branch
            const size_t off = base_off + (size_t)rloc * D_DIM;
            const float4* po = (const float4*)(outputs + off);
            const float4* pt = (const float4*)(orig    + off);
            const float4 o0 = po[lane];
            const float4 o1 = po[lane + 64];
            const float4 t0 = pt[lane];
            const float4 t1 = pt[lane + 64];
            float s;
            {
                const float dx = o0.x - t0.x, dy = o0.y - t0.y;
                const float dz = o0.z - t0.z, dw = o0.w - t0.w;
                s = dx * dx + dy * dy + dz * dz + dw * dw;
            }
            {
                const float dx = o1.x - t1.x, dy = o1.y - t1.y;
                const float dz = o1.z - t1.z, dw = o1.w - t1.w;
                s += dx * dx + dy * dy + dz * dz + dw * dw;
            }
            acc = fmaf(wgt, s, acc);
        }
    }

    // ---- Phase 3: reduction ----
    #pragma unroll
    for (int off = 32; off > 0; off >>= 1)
        acc += __shfl_down(acc, off, 64);

    if (lane == 0) sred[wid] = acc;
    __syncthreads();

    if (tid == 0)
        atomicAdd(out, sred[0] + sred[1] + sred[2] + sred[3]);
}

extern "C" void kernel_launch(void* const* d_in, const int* in_sizes, int n_in,
                              void* d_out, int out_size, void* d_ws, size_t ws_size,
                              hipStream_t stream) {
    const float* outputs   = (const float*)d_in[0];
    const float* orig      = (const float*)d_in[1];
    const int*   mask_id   = (const int*)d_in[2];
    const int*   unmask_id = (const int*)d_in[3];
    float* out = (float*)d_out;

    // d_out is re-poisoned to 0xAA before every timed launch — zero it here.
    // (4-byte fill, ~2 us dispatch.)
    hipMemsetAsync(out, 0, sizeof(float), stream);

    // NOTE: deliberately NO d_ws usage this round — testing whether the
    // 1-GiB fillBufferAligned dispatches (3x160 us in the profile) are
    // workspace poison serialized into the timed window.
    fused_mae_loss<<<GRID, BLOCK, 0, stream>>>(outputs, orig, mask_id, unmask_id, out);
}